// Round 2
// baseline (2088.669 us; speedup 1.0000x reference)
//
#include <hip/hip_runtime.h>
#include <math.h>

#define NW   5
#define PRJ  14
#define CCH  512
#define PP   100
#define NQ   375
#define NS   70
#define NPAIR (NQ*NW)

// workspace offsets (in floats) — total 452,435 floats = 1.73 MB
#define OFF_PROTO   0          // 5*512*100 = 256000
#define OFF_PAVG    256000     // 2560
#define OFF_QAVG    258560     // 375*512 = 192000
#define OFF_LOGITS  450560     // 1875

// ---------------- K1: proto = mean over shots; proto_avg ----------------
__global__ void k_proto(const float* __restrict__ feat, float* __restrict__ ws) {
    int nc = blockIdx.x;            // n*512 + c
    int n  = nc >> 9;
    int p  = threadIdx.x;
    float s = 0.f;
    if (p < PP) {
        const float* base = feat + (size_t)((n * PRJ) * CCH) * PP + (size_t)(nc & 511) * PP + p;
        #pragma unroll
        for (int k = 0; k < PRJ; ++k) s += base[(size_t)k * CCH * PP];
        s *= (1.f / PRJ);
        ws[OFF_PROTO + nc * PP + p] = s;
    }
    float v = (p < PP) ? s : 0.f;
    #pragma unroll
    for (int off = 32; off; off >>= 1) v += __shfl_down(v, off);
    __shared__ float red[2];
    if ((threadIdx.x & 63) == 0) red[threadIdx.x >> 6] = v;
    __syncthreads();
    if (threadIdx.x == 0) ws[OFF_PAVG + nc] = (red[0] + red[1]) * (1.f / PP);
}

// ---------------- K2: query spatial average (per m,c) -------------------
__global__ void k_qavg(const float* __restrict__ query, float* __restrict__ ws) {
    int m = blockIdx.x;
    for (int c = threadIdx.x; c < CCH; c += blockDim.x) {
        const float4* row = (const float4*)(query + ((size_t)m * CCH + c) * PP);
        float s = 0.f;
        #pragma unroll
        for (int i = 0; i < PP / 4; ++i) { float4 v = row[i]; s += (v.x + v.y) + (v.z + v.w); }
        ws[OFF_QAVG + m * CCH + c] = s * (1.f / PP);
    }
}

// ------- K3: per-pair fused: stats + weights + cost matmul + Sinkhorn ----
__global__ __launch_bounds__(256) void k_pair(const float* __restrict__ query, float* __restrict__ ws) {
    __shared__ __align__(16) float cost[PP * 101];       // padded stride 101
    __shared__ __align__(16) float qs[1616];             // 16x100 tile + zero pad
    __shared__ __align__(16) float psh[1616];
    __shared__ float pavg_s[CCH], qavg_s[CCH];
    __shared__ float f2[PP], g2[PP], lr[PP], lc[PP];
    __shared__ float qnl[PP], pnl[PP], chql[PP], chpl[PP];
    __shared__ float red[8];

    int pair = blockIdx.x;
    int m = pair / NW;
    int n = pair - m * NW;
    int tid = threadIdx.x;
    int ta = tid & 15, tb = tid >> 4;

    // zero the tile pads once (read range of the unguarded tile loads is
    // [0,1612); [1600,1616) is never written by staging -> define it)
    if (tid < 16)       qs [1600 + tid] = 0.f;
    else if (tid < 32)  psh[1584 + tid] = 0.f;
    for (int i = tid; i < CCH; i += 256) {
        pavg_s[i] = ws[OFF_PAVG + n * CCH + i];
        qavg_s[i] = ws[OFF_QAVG + m * CCH + i];
    }

    float acc[7][7];
    #pragma unroll
    for (int i = 0; i < 7; ++i)
        #pragma unroll
        for (int j = 0; j < 7; ++j) acc[i][j] = 0.f;
    float qsum = 0.f, qsq = 0.f, psum = 0.f, psq = 0.f, w1 = 0.f, w2 = 0.f;

    const float* qbase = query + (size_t)m * CCH * PP;
    const float* pbase = ws + OFF_PROTO + (size_t)n * CCH * PP;

    for (int c0 = 0; c0 < CCH; c0 += 16) {
        const float4* gq = (const float4*)(qbase + (size_t)c0 * PP);
        const float4* gp = (const float4*)(pbase + (size_t)c0 * PP);
        for (int i = tid; i < 400; i += 256) {
            ((float4*)qs)[i]  = gq[i];
            ((float4*)psh)[i] = gp[i];
        }
        __syncthreads();
        // fused channel stats + w1/w2 dot products (one thread per node p)
        if (tid < PP) {
            #pragma unroll
            for (int cc = 0; cc < 16; ++cc) {
                float xq = qs [cc * PP + tid];
                float xp = psh[cc * PP + tid];
                qsum += xq; qsq = fmaf(xq, xq, qsq);
                psum += xp; psq = fmaf(xp, xp, psq);
                w1 = fmaf(xq, pavg_s[c0 + cc], w1);
                w2 = fmaf(xp, qavg_s[c0 + cc], w2);
            }
        }
        // 100x100 cross-product tile (7x7 per thread, 16x16 threads)
        for (int cc = 0; cc < 16; ++cc) {
            float qv[7], pv[7];
            #pragma unroll
            for (int i = 0; i < 7; ++i) qv[i] = qs [cc * PP + ta + 16 * i];
            #pragma unroll
            for (int j = 0; j < 7; ++j) pv[j] = psh[cc * PP + tb + 16 * j];
            #pragma unroll
            for (int i = 0; i < 7; ++i)
                #pragma unroll
                for (int j = 0; j < 7; ++j) acc[i][j] = fmaf(qv[i], pv[j], acc[i][j]);
        }
        __syncthreads();
    }

    // stats -> LDS; weight normalization
    if (tid < PP) {
        float muq = qsum * (1.f / CCH);
        chql[tid] = muq;
        qnl[tid]  = fmaf(-(float)CCH * muq, muq, qsq);
        float mup = psum * (1.f / CCH);
        chpl[tid] = mup;
        pnl[tid]  = fmaf(-(float)CCH * mup, mup, psq);
        f2[tid] = 0.f; g2[tid] = 0.f;
    }
    float v1 = (tid < PP) ? (fmaxf(w1, 0.f) + 0.00101f) : 0.f;
    float v2 = (tid < PP) ? (fmaxf(w2, 0.f) + 0.00101f) : 0.f;
    float s1 = v1, s2 = v2;
    #pragma unroll
    for (int off = 32; off; off >>= 1) { s1 += __shfl_down(s1, off); s2 += __shfl_down(s2, off); }
    if ((tid & 63) == 0) { red[tid >> 6] = s1; red[4 + (tid >> 6)] = s2; }
    __syncthreads();
    float t1 = (red[0] + red[1]) + (red[2] + red[3]);
    float t2 = (red[4] + red[5]) + (red[6] + red[7]);
    if (tid < PP) {
        lr[tid] = __log2f(v1 * (100.f / t1));
        lc[tid] = __log2f(v2 * (100.f / t2));
    }

    // sqd into acc, find block max
    float mymax = -1e30f;
    #pragma unroll
    for (int i = 0; i < 7; ++i) {
        int a = ta + 16 * i;
        if (a < PP) {
            #pragma unroll
            for (int j = 0; j < 7; ++j) {
                int b = tb + 16 * j;
                if (b < PP) {
                    float cr  = fmaf(-(float)CCH * chql[a], chpl[b], acc[i][j]);
                    float sqd = qnl[a] + pnl[b] - 2.f * cr;
                    acc[i][j] = sqd;
                    mymax = fmaxf(mymax, sqd);
                }
            }
        }
    }
    float v = mymax;
    #pragma unroll
    for (int off = 32; off; off >>= 1) v = fmaxf(v, __shfl_down(v, off));
    __syncthreads();                       // red was read above (t1/t2)
    if ((tid & 63) == 0) red[tid >> 6] = v;
    __syncthreads();
    v = fmaxf(fmaxf(red[0], red[1]), fmaxf(red[2], red[3]));
    float scale = v + 1e-6f;
    // cost2 = sqd/scale * (1/eps) * log2(e)
    float k2 = (1.f / scale) * 20.f * 1.44269504088896f;
    #pragma unroll
    for (int i = 0; i < 7; ++i) {
        int a = ta + 16 * i;
        if (a < PP) {
            #pragma unroll
            for (int j = 0; j < 7; ++j) {
                int b = tb + 16 * j;
                if (b < PP) cost[a * 101 + b] = acc[i][j] * k2;
            }
        }
    }
    __syncthreads();

    // Sinkhorn, 50 iterations, base-2 log domain scaled by 1/eps
    int r_  = tid >> 1;
    int hf  = tid & 1;
    int base = hf * 50;
    bool sact = tid < 200;
    for (int it = 0; it < 50; ++it) {
        if (sact) {
            const float* crow = cost + r_ * 101 + base;
            const float* gg = g2 + base;
            float mx = -1e30f;
            for (int j = 0; j < 50; ++j) mx = fmaxf(mx, gg[j] - crow[j]);
            mx = fmaxf(mx, __shfl_xor(mx, 1));
            float sm = 0.f;
            for (int j = 0; j < 50; ++j) sm += exp2f(gg[j] - crow[j] - mx);
            sm += __shfl_xor(sm, 1);
            if (!hf) f2[r_] = lr[r_] - mx - __log2f(sm);
        }
        __syncthreads();
        if (sact) {
            const float* ccol = cost + base * 101 + r_;
            const float* ff = f2 + base;
            float mx = -1e30f;
            for (int i = 0; i < 50; ++i) mx = fmaxf(mx, ff[i] - ccol[i * 101]);
            mx = fmaxf(mx, __shfl_xor(mx, 1));
            float sm = 0.f;
            for (int i = 0; i < 50; ++i) sm += exp2f(ff[i] - ccol[i * 101] - mx);
            sm += __shfl_xor(sm, 1);
            if (!hf) g2[r_] = lc[r_] - mx - __log2f(sm);
        }
        __syncthreads();
    }

    // logits contribution: sum sim*flow
    // sqd = cost2 * scale * eps * ln2 ; sim = 1 - sqd ; flow = 2^(f2+g2-cost2)
    float ksim = scale * (0.05f * 0.69314718056f);
    float lsum = 0.f;
    #pragma unroll
    for (int i = 0; i < 7; ++i) {
        int a = ta + 16 * i;
        if (a < PP) {
            float fa = f2[a];
            #pragma unroll
            for (int j = 0; j < 7; ++j) {
                int b = tb + 16 * j;
                if (b < PP) {
                    float cv = cost[a * 101 + b];
                    float fl = exp2f(fa + g2[b] - cv);
                    lsum = fmaf(1.f - cv * ksim, fl, lsum);
                }
            }
        }
    }
    #pragma unroll
    for (int off = 32; off; off >>= 1) lsum += __shfl_down(lsum, off);
    __syncthreads();
    if ((tid & 63) == 0) red[tid >> 6] = lsum;
    __syncthreads();
    if (tid == 0)
        ws[OFF_LOGITS + pair] = (red[0] + red[1] + red[2] + red[3]) * 0.125f;
}

// ---------------- K4: log-softmax + loss --------------------------------
__global__ void k_final(const int* __restrict__ label, const float* __restrict__ ws,
                        float* __restrict__ out) {
    int t = threadIdx.x;   // 384 threads
    float contrib = 0.f;
    if (t < NQ) {
        float lg[NW];
        #pragma unroll
        for (int n = 0; n < NW; ++n) lg[n] = ws[OFF_LOGITS + t * NW + n];
        float mx = lg[0];
        #pragma unroll
        for (int n = 1; n < NW; ++n) mx = fmaxf(mx, lg[n]);
        float s = 0.f;
        #pragma unroll
        for (int n = 0; n < NW; ++n) s += expf(lg[n] - mx);
        float lse = mx + logf(s);
        int lab = label[t];
        #pragma unroll
        for (int n = 0; n < NW; ++n) {
            float lp = lg[n] - lse;
            out[t * NW + n] = lp;
            if (n == lab) contrib = -lp;
        }
    }
    #pragma unroll
    for (int off = 32; off; off >>= 1) contrib += __shfl_down(contrib, off);
    __shared__ float red[6];
    if ((t & 63) == 0) red[t >> 6] = contrib;
    __syncthreads();
    if (t == 0) {
        float s = 0.f;
        #pragma unroll
        for (int i = 0; i < 6; ++i) s += red[i];
        out[NQ * NW] = s * (1.f / NQ);
    }
}

extern "C" void kernel_launch(void* const* d_in, const int* in_sizes, int n_in,
                              void* d_out, int out_size, void* d_ws, size_t ws_size,
                              hipStream_t stream) {
    const float* feat  = (const float*)d_in[0];
    const int*   label = (const int*)d_in[1];
    float* out = (float*)d_out;
    float* ws  = (float*)d_ws;
    const float* query = feat + (size_t)NS * CCH * PP;

    k_proto <<<NW * CCH, 128, 0, stream>>>(feat, ws);
    k_qavg  <<<NQ,       128, 0, stream>>>(query, ws);
    k_pair  <<<NPAIR,    256, 0, stream>>>(query, ws);
    k_final <<<1,        384, 0, stream>>>(label, ws, out);
}

// Round 3
// 1084.349 us; speedup vs baseline: 1.9262x; 1.9262x over previous
//
#include <hip/hip_runtime.h>
#include <math.h>

#define NW   5
#define PRJ  14
#define CCH  512
#define PP   100
#define NQ   375
#define NS   70
#define NPAIR (NQ*NW)

// workspace offsets (in floats) — total 452,435 floats = 1.81 MB
#define OFF_PROTO   0          // 5*512*100 = 256000
#define OFF_PAVG    256000     // 2560
#define OFF_QAVG    258560     // 375*512 = 192000
#define OFF_LOGITS  450560     // 1875

// ---------------- K1: proto = mean over shots; proto_avg ----------------
__global__ void k_proto(const float* __restrict__ feat, float* __restrict__ ws) {
    int nc = blockIdx.x;            // n*512 + c
    int n  = nc >> 9;
    int p  = threadIdx.x;
    float s = 0.f;
    if (p < PP) {
        const float* base = feat + (size_t)((n * PRJ) * CCH) * PP + (size_t)(nc & 511) * PP + p;
        #pragma unroll
        for (int k = 0; k < PRJ; ++k) s += base[(size_t)k * CCH * PP];
        s *= (1.f / PRJ);
        ws[OFF_PROTO + nc * PP + p] = s;
    }
    float v = (p < PP) ? s : 0.f;
    #pragma unroll
    for (int off = 32; off; off >>= 1) v += __shfl_down(v, off);
    __shared__ float red[2];
    if ((threadIdx.x & 63) == 0) red[threadIdx.x >> 6] = v;
    __syncthreads();
    if (threadIdx.x == 0) ws[OFF_PAVG + nc] = (red[0] + red[1]) * (1.f / PP);
}

// ---------------- K2: query spatial average (per m,c) -------------------
__global__ void k_qavg(const float* __restrict__ query, float* __restrict__ ws) {
    int m = blockIdx.x;
    for (int c = threadIdx.x; c < CCH; c += blockDim.x) {
        const float4* row = (const float4*)(query + ((size_t)m * CCH + c) * PP);
        float s = 0.f;
        #pragma unroll
        for (int i = 0; i < PP / 4; ++i) { float4 v = row[i]; s += (v.x + v.y) + (v.z + v.w); }
        ws[OFF_QAVG + m * CCH + c] = s * (1.f / PP);
    }
}

// ------- K3: per-pair fused: stats + weights + cost matmul + Sinkhorn ----
// LDS: buf aliases {staging tiles} then {cost matrix, stride 101}.
// Sinkhorn is register-resident: thread (r_,hf) keeps cost row-half and
// column-half in VGPRs; only f/g (100 floats each) live in LDS per pass.
__global__ __launch_bounds__(256, 3) void k_pair(const float* __restrict__ query, float* __restrict__ ws) {
    __shared__ __align__(16) float buf[PP * 101];     // 40.4 KB: tiles / cost alias
    __shared__ __align__(16) float f2s[104], g2s[104];// halves at [0,50) and [52,102)
    __shared__ float pavg_s[CCH], qavg_s[CCH];
    __shared__ float lr[PP], lc[PP];
    __shared__ float qnl[PP], pnl[PP], chql[PP], chpl[PP];
    __shared__ float red[8];

    float* qs  = buf;          // 16x100 tile + 16 zero pad
    float* psh = buf + 1616;

    int pair = blockIdx.x;
    int m = pair / NW;
    int n = pair - m * NW;
    int tid = threadIdx.x;
    int ta = tid & 15, tb = tid >> 4;

    // zero the tile pads once (unguarded 7x7 reads reach index 1611)
    if (tid < 16)      qs [1600 + tid]      = 0.f;
    else if (tid < 32) psh[1600 + tid - 16] = 0.f;
    for (int i = tid; i < CCH; i += 256) {
        pavg_s[i] = ws[OFF_PAVG + n * CCH + i];
        qavg_s[i] = ws[OFF_QAVG + m * CCH + i];
    }

    float acc[7][7];
    #pragma unroll
    for (int i = 0; i < 7; ++i)
        #pragma unroll
        for (int j = 0; j < 7; ++j) acc[i][j] = 0.f;
    float qsum = 0.f, qsq = 0.f, psum = 0.f, psq = 0.f, w1 = 0.f, w2 = 0.f;

    const float* qbase = query + (size_t)m * CCH * PP;
    const float* pbase = ws + OFF_PROTO + (size_t)n * CCH * PP;

    for (int c0 = 0; c0 < CCH; c0 += 16) {
        const float4* gq = (const float4*)(qbase + (size_t)c0 * PP);
        const float4* gp = (const float4*)(pbase + (size_t)c0 * PP);
        for (int i = tid; i < 400; i += 256) {
            ((float4*)qs)[i]  = gq[i];
            ((float4*)psh)[i] = gp[i];
        }
        __syncthreads();
        if (tid < PP) {
            #pragma unroll
            for (int cc = 0; cc < 16; ++cc) {
                float xq = qs [cc * PP + tid];
                float xp = psh[cc * PP + tid];
                qsum += xq; qsq = fmaf(xq, xq, qsq);
                psum += xp; psq = fmaf(xp, xp, psq);
                w1 = fmaf(xq, pavg_s[c0 + cc], w1);
                w2 = fmaf(xp, qavg_s[c0 + cc], w2);
            }
        }
        for (int cc = 0; cc < 16; ++cc) {
            float qv[7], pv[7];
            #pragma unroll
            for (int i = 0; i < 7; ++i) qv[i] = qs [cc * PP + ta + 16 * i];
            #pragma unroll
            for (int j = 0; j < 7; ++j) pv[j] = psh[cc * PP + tb + 16 * j];
            #pragma unroll
            for (int i = 0; i < 7; ++i)
                #pragma unroll
                for (int j = 0; j < 7; ++j) acc[i][j] = fmaf(qv[i], pv[j], acc[i][j]);
        }
        __syncthreads();
    }

    // stats -> LDS; weight normalization
    if (tid < PP) {
        float muq = qsum * (1.f / CCH);
        chql[tid] = muq;
        qnl[tid]  = fmaf(-(float)CCH * muq, muq, qsq);
        float mup = psum * (1.f / CCH);
        chpl[tid] = mup;
        pnl[tid]  = fmaf(-(float)CCH * mup, mup, psq);
    }
    float v1 = (tid < PP) ? (fmaxf(w1, 0.f) + 0.00101f) : 0.f;
    float v2 = (tid < PP) ? (fmaxf(w2, 0.f) + 0.00101f) : 0.f;
    float s1 = v1, s2 = v2;
    #pragma unroll
    for (int off = 32; off; off >>= 1) { s1 += __shfl_down(s1, off); s2 += __shfl_down(s2, off); }
    if ((tid & 63) == 0) { red[tid >> 6] = s1; red[4 + (tid >> 6)] = s2; }
    __syncthreads();
    float t1 = (red[0] + red[1]) + (red[2] + red[3]);
    float t2 = (red[4] + red[5]) + (red[6] + red[7]);
    if (tid < PP) {
        lr[tid] = __log2f(v1 * (100.f / t1));
        lc[tid] = __log2f(v2 * (100.f / t2));
    }

    // sqd into acc, block max
    float mymax = -1e30f;
    #pragma unroll
    for (int i = 0; i < 7; ++i) {
        int a = ta + 16 * i;
        if (a < PP) {
            #pragma unroll
            for (int j = 0; j < 7; ++j) {
                int b = tb + 16 * j;
                if (b < PP) {
                    float cr  = fmaf(-(float)CCH * chql[a], chpl[b], acc[i][j]);
                    float sqd = qnl[a] + pnl[b] - 2.f * cr;
                    acc[i][j] = sqd;
                    mymax = fmaxf(mymax, sqd);
                }
            }
        }
    }
    float v = mymax;
    #pragma unroll
    for (int off = 32; off; off >>= 1) v = fmaxf(v, __shfl_down(v, off));
    __syncthreads();                       // red was read above (t1/t2)
    if ((tid & 63) == 0) red[tid >> 6] = v;
    __syncthreads();
    v = fmaxf(fmaxf(red[0], red[1]), fmaxf(red[2], red[3]));
    float scale = v + 1e-6f;
    float k2 = (1.f / scale) * 20.f * 1.44269504088896f;   // 1/(eps*ln2*scale)
    // write scaled cost into buf (tiles are dead past the last barrier)
    #pragma unroll
    for (int i = 0; i < 7; ++i) {
        int a = ta + 16 * i;
        if (a < PP) {
            #pragma unroll
            for (int j = 0; j < 7; ++j) {
                int b = tb + 16 * j;
                if (b < PP) buf[a * 101 + b] = acc[i][j] * k2;
            }
        }
    }
    __syncthreads();

    // ---- register-resident Sinkhorn ----
    int r_   = tid >> 1;
    int hf   = tid & 1;
    int base = hf * 50;
    int base2 = hf * 52;
    bool sact = tid < 200;
    float crow[50], ccol[50];
    if (sact) {
        #pragma unroll
        for (int j = 0; j < 50; ++j) crow[j] = buf[r_ * 101 + base + j];
        #pragma unroll
        for (int i = 0; i < 50; ++i) ccol[i] = buf[(base + i) * 101 + r_];
    }
    if (tid < 104) { f2s[tid] = 0.f; g2s[tid] = 0.f; }
    __syncthreads();

    int widx = (r_ < 50) ? r_ : (r_ + 2);
    for (int it = 0; it < 50; ++it) {
        if (sact) {
            const float4* gp4 = (const float4*)(g2s + base2);
            float s0 = 0.f, sx1 = 0.f, sx2 = 0.f, sx3 = 0.f;
            #pragma unroll
            for (int q = 0; q < 12; ++q) {
                float4 G = gp4[q];
                s0  += exp2f(G.x - crow[4 * q]);
                sx1 += exp2f(G.y - crow[4 * q + 1]);
                sx2 += exp2f(G.z - crow[4 * q + 2]);
                sx3 += exp2f(G.w - crow[4 * q + 3]);
            }
            s0  += exp2f(g2s[base2 + 48] - crow[48]);
            sx1 += exp2f(g2s[base2 + 49] - crow[49]);
            float sm = (s0 + sx1) + (sx2 + sx3);
            sm += __shfl_xor(sm, 1);
            if (!hf) f2s[widx] = lr[r_] - __log2f(sm);
        }
        __syncthreads();
        if (sact) {
            const float4* fp4 = (const float4*)(f2s + base2);
            float s0 = 0.f, sx1 = 0.f, sx2 = 0.f, sx3 = 0.f;
            #pragma unroll
            for (int q = 0; q < 12; ++q) {
                float4 F = fp4[q];
                s0  += exp2f(F.x - ccol[4 * q]);
                sx1 += exp2f(F.y - ccol[4 * q + 1]);
                sx2 += exp2f(F.z - ccol[4 * q + 2]);
                sx3 += exp2f(F.w - ccol[4 * q + 3]);
            }
            s0  += exp2f(f2s[base2 + 48] - ccol[48]);
            sx1 += exp2f(f2s[base2 + 49] - ccol[49]);
            float sm = (s0 + sx1) + (sx2 + sx3);
            sm += __shfl_xor(sm, 1);
            if (!hf) g2s[widx] = lc[r_] - __log2f(sm);
        }
        __syncthreads();
    }

    // epilogue: lsum = sum over own row-half of (1 - sqd)*flow
    float ksim = scale * (0.05f * 0.69314718056f);
    float lsum = 0.f;
    if (sact) {
        float fv = f2s[widx];
        const float4* gp4 = (const float4*)(g2s + base2);
        #pragma unroll
        for (int q = 0; q < 12; ++q) {
            float4 G = gp4[q];
            float c0_ = crow[4 * q],     c1_ = crow[4 * q + 1];
            float c2_ = crow[4 * q + 2], c3_ = crow[4 * q + 3];
            lsum = fmaf(1.f - c0_ * ksim, exp2f(fv + G.x - c0_), lsum);
            lsum = fmaf(1.f - c1_ * ksim, exp2f(fv + G.y - c1_), lsum);
            lsum = fmaf(1.f - c2_ * ksim, exp2f(fv + G.z - c2_), lsum);
            lsum = fmaf(1.f - c3_ * ksim, exp2f(fv + G.w - c3_), lsum);
        }
        {
            float c0_ = crow[48], c1_ = crow[49];
            lsum = fmaf(1.f - c0_ * ksim, exp2f(fv + g2s[base2 + 48] - c0_), lsum);
            lsum = fmaf(1.f - c1_ * ksim, exp2f(fv + g2s[base2 + 49] - c1_), lsum);
        }
    }
    #pragma unroll
    for (int off = 32; off; off >>= 1) lsum += __shfl_down(lsum, off);
    if ((tid & 63) == 0) red[tid >> 6] = lsum;
    __syncthreads();
    if (tid == 0)
        ws[OFF_LOGITS + pair] = ((red[0] + red[1]) + (red[2] + red[3])) * 0.125f;
}

// ---------------- K4: log-softmax + loss --------------------------------
__global__ void k_final(const int* __restrict__ label, const float* __restrict__ ws,
                        float* __restrict__ out) {
    int t = threadIdx.x;   // 384 threads
    float contrib = 0.f;
    if (t < NQ) {
        float lg[NW];
        #pragma unroll
        for (int n = 0; n < NW; ++n) lg[n] = ws[OFF_LOGITS + t * NW + n];
        float mx = lg[0];
        #pragma unroll
        for (int n = 1; n < NW; ++n) mx = fmaxf(mx, lg[n]);
        float s = 0.f;
        #pragma unroll
        for (int n = 0; n < NW; ++n) s += expf(lg[n] - mx);
        float lse = mx + logf(s);
        int lab = label[t];
        #pragma unroll
        for (int n = 0; n < NW; ++n) {
            float lp = lg[n] - lse;
            out[t * NW + n] = lp;
            if (n == lab) contrib = -lp;
        }
    }
    #pragma unroll
    for (int off = 32; off; off >>= 1) contrib += __shfl_down(contrib, off);
    __shared__ float red[6];
    if ((t & 63) == 0) red[t >> 6] = contrib;
    __syncthreads();
    if (t == 0) {
        float s = 0.f;
        #pragma unroll
        for (int i = 0; i < 6; ++i) s += red[i];
        out[NQ * NW] = s * (1.f / NQ);
    }
}

extern "C" void kernel_launch(void* const* d_in, const int* in_sizes, int n_in,
                              void* d_out, int out_size, void* d_ws, size_t ws_size,
                              hipStream_t stream) {
    const float* feat  = (const float*)d_in[0];
    const int*   label = (const int*)d_in[1];
    float* out = (float*)d_out;
    float* ws  = (float*)d_ws;
    const float* query = feat + (size_t)NS * CCH * PP;

    k_proto <<<NW * CCH, 128, 0, stream>>>(feat, ws);
    k_qavg  <<<NQ,       128, 0, stream>>>(query, ws);
    k_pair  <<<NPAIR,    256, 0, stream>>>(query, ws);
    k_final <<<1,        384, 0, stream>>>(label, ws, out);
}

// Round 4
// 468.069 us; speedup vs baseline: 4.4623x; 2.3166x over previous
//
#include <hip/hip_runtime.h>
#include <math.h>

#define NW   5
#define PRJ  14
#define CCH  512
#define PP   100
#define NQ   375
#define NS   70
#define NPAIR (NQ*NW)

// ws offsets (floats) — total 490,435 floats = 1.87 MB
#define OFF_PROTO   0          // 5*512*100 = 256000
#define OFF_PAVG    256000     // 2560
#define OFF_QAVG    258560     // 192000
#define OFF_QSQ     450560     // 37500
#define OFF_PSQ     488060     // 500
#define OFF_LOGITS  488560     // 1875

typedef short short8 __attribute__((ext_vector_type(8)));
typedef float f32x16 __attribute__((ext_vector_type(16)));

__device__ __forceinline__ int SWZ(int n) { return n ^ ((n >> 2) & 7); }

// ---------------- K1: proto = mean over shots; proto_avg ----------------
__global__ void k_proto(const float* __restrict__ feat, float* __restrict__ ws) {
    int nc = blockIdx.x;            // n*512 + c
    int n  = nc >> 9;
    int p  = threadIdx.x;
    float s = 0.f;
    if (p < PP) {
        const float* base = feat + (size_t)((n * PRJ) * CCH) * PP + (size_t)(nc & 511) * PP + p;
        #pragma unroll
        for (int k = 0; k < PRJ; ++k) s += base[(size_t)k * CCH * PP];
        s *= (1.f / PRJ);
        ws[OFF_PROTO + nc * PP + p] = s;
    }
    float v = (p < PP) ? s : 0.f;
    #pragma unroll
    for (int off = 32; off; off >>= 1) v += __shfl_down(v, off);
    __shared__ float red[2];
    if ((threadIdx.x & 63) == 0) red[threadIdx.x >> 6] = v;
    __syncthreads();
    if (threadIdx.x == 0) ws[OFF_PAVG + nc] = (red[0] + red[1]) * (1.f / PP);
}

// ------- K2: per-image transpose-stats: sumsq per node (+ optional avg per ch)
__global__ __launch_bounds__(256) void k_qstat(const float* __restrict__ src,
                                               float* __restrict__ dst_sq,
                                               float* __restrict__ dst_avg) {
    __shared__ __align__(16) float t[6400];
    int b = blockIdx.x, tid = threadIdx.x;
    const float* base = src + (size_t)b * CCH * PP;
    float qsq = 0.f;
    for (int c0 = 0; c0 < CCH; c0 += 64) {
        __syncthreads();
        const float4* g = (const float4*)(base + (size_t)c0 * PP);
        for (int i = tid; i < 1600; i += 256) ((float4*)t)[i] = g[i];
        __syncthreads();
        if (tid < PP) {
            #pragma unroll 8
            for (int c = 0; c < 64; ++c) { float x = t[c * PP + tid]; qsq = fmaf(x, x, qsq); }
        } else if (tid >= 128 && tid < 192) {
            int ch = tid - 128;
            const float4* row = (const float4*)(t + ch * PP);
            float s = 0.f;
            #pragma unroll
            for (int i = 0; i < 25; ++i) { float4 v = row[i]; s += (v.x + v.y) + (v.z + v.w); }
            if (dst_avg) dst_avg[(size_t)b * CCH + c0 + ch] = s * (1.f / PP);
        }
    }
    if (tid < PP) dst_sq[b * PP + tid] = qsq;
}

// ------- K3: per-pair: MFMA cost matmul + weights + linear Sinkhorn ------
__global__ __launch_bounds__(256, 3) void k_pair(const float* __restrict__ query,
                                                 float* __restrict__ ws) {
    // SH aliases: tiles during matmul (A_hi 0 / A_lo 8192 / B_hi 16384 / B_lo 24576, 32KB)
    // then Gibbs K (bf16-pair dwords, rows stride 216B) at 0 and KT at 21600 (43.2KB)
    __shared__ __align__(16) char SH[43200];
    __shared__ __align__(16) float uvec[112], vvec[112];   // halves at [0,50) and [56,106)
    __shared__ float wrL[PP], wcL[PP], qnl[PP], pnl[PP], sqv[PP], spv[PP];
    __shared__ float red[8];

    int pair = blockIdx.x;
    int m = pair / NW;
    int n = pair - m * NW;
    int tid = threadIdx.x;
    int lane = tid & 63, wid = tid >> 6;
    int lrow = lane & 31, lhi = lane >> 5;

    const float* qb = query + (size_t)m * CCH * PP;
    const float* pb = ws + OFF_PROTO + (size_t)n * CCH * PP;
    const float* qavg_g = ws + OFF_QAVG + (size_t)m * CCH;
    const float* pavg_g = ws + OFF_PAVG + (size_t)n * CCH;

    // init pad slots once: slot 100 (=SWZ(101)) = ones row/col, slots 102..127 = 0.
    // (slot 101 = SWZ(100) holds the avg vector, rewritten per k-tile below)
    for (int idx = tid; idx < 448; idx += 256) {
        int s_i = idx % 28; int rest = idx / 28;
        int s = 100 + s_i;
        if (s == 101) continue;
        int k4 = rest & 3, pl = (rest >> 2) & 1, mt = rest >> 3;
        uint4 val = (s == 100 && pl == 0)
                  ? make_uint4(0x3F803F80u, 0x3F803F80u, 0x3F803F80u, 0x3F803F80u)
                  : make_uint4(0u, 0u, 0u, 0u);
        *(uint4*)&SH[mt * 16384 + pl * 8192 + ((k4 << 7) + s) * 16] = val;
    }

    f32x16 acc[4];
    #pragma unroll
    for (int tc = 0; tc < 4; ++tc)
        #pragma unroll
        for (int e = 0; e < 16; ++e) acc[tc][e] = 0.f;

    int arow16 = SWZ(32 * wid + lrow) * 16;
    int bcol16[4];
    #pragma unroll
    for (int tc = 0; tc < 4; ++tc) bcol16[tc] = SWZ(32 * tc + lrow) * 16;

    for (int kt = 0; kt < 16; ++kt) {
        int c0 = kt * 32;
        // stage: f32 -> bf16 hi/lo split, ch-pair packed dword writes, SWZ node slots
        for (int idx = tid; idx < 800; idx += 256) {
            int mt = idx >= 400;
            int i = idx - (mt ? 400 : 0);
            int cp = i / 25, n4 = i - cp * 25;
            const float* src = (mt ? pb : qb) + (size_t)(c0 + 2 * cp) * PP + n4 * 4;
            float4 x0 = *(const float4*)src;
            float4 x1 = *(const float4*)(src + PP);
            const float* p0 = (const float*)&x0;
            const float* p1 = (const float*)&x1;
            int mb = mt ? 16384 : 0;
            int basedw = ((cp >> 2) << 7);
            int dwb = (cp & 3) * 4;
            #pragma unroll
            for (int i4 = 0; i4 < 4; ++i4) {
                int node = n4 * 4 + i4;
                float a0 = p0[i4], a1 = p1[i4];
                uint h0 = __float_as_uint(a0) & 0xFFFF0000u;
                uint h1 = __float_as_uint(a1) & 0xFFFF0000u;
                float r0 = a0 - __uint_as_float(h0);
                float r1 = a1 - __uint_as_float(h1);
                uint hp = (h0 >> 16) | h1;
                uint lp = (__float_as_uint(r0) >> 16) | (__float_as_uint(r1) & 0xFFFF0000u);
                int off = (basedw + SWZ(node)) * 16 + dwb;
                *(uint*)&SH[mb + off] = hp;
                *(uint*)&SH[mb + 8192 + off] = lp;
            }
        }
        // avg row/col (physical slot 101): A row100=qavg, B col100=pavg
        if (tid < 32) {
            int mt = tid >> 4, cp = tid & 15;
            const float* av = mt ? pavg_g : qavg_g;
            float a0 = av[c0 + 2 * cp], a1 = av[c0 + 2 * cp + 1];
            uint h0 = __float_as_uint(a0) & 0xFFFF0000u;
            uint h1 = __float_as_uint(a1) & 0xFFFF0000u;
            float r0 = a0 - __uint_as_float(h0);
            float r1 = a1 - __uint_as_float(h1);
            uint hp = (h0 >> 16) | h1;
            uint lp = (__float_as_uint(r0) >> 16) | (__float_as_uint(r1) & 0xFFFF0000u);
            int off = (((cp >> 2) << 7) + 101) * 16 + (cp & 3) * 4;
            *(uint*)&SH[mt * 16384 + off] = hp;
            *(uint*)&SH[mt * 16384 + 8192 + off] = lp;
        }
        __syncthreads();
        #pragma unroll
        for (int s = 0; s < 2; ++s) {
            int kb = (2 * s + lhi) * 2048;
            short8 ah = *(const short8*)&SH[kb + arow16];
            short8 al = *(const short8*)&SH[8192 + kb + arow16];
            #pragma unroll
            for (int tc = 0; tc < 4; ++tc) {
                short8 bh = *(const short8*)&SH[16384 + kb + bcol16[tc]];
                short8 bl = *(const short8*)&SH[24576 + kb + bcol16[tc]];
                acc[tc] = __builtin_amdgcn_mfma_f32_32x32x16_bf16(ah, bh, acc[tc], 0, 0, 0);
                acc[tc] = __builtin_amdgcn_mfma_f32_32x32x16_bf16(ah, bl, acc[tc], 0, 0, 0);
                acc[tc] = __builtin_amdgcn_mfma_f32_32x32x16_bf16(al, bh, acc[tc], 0, 0, 0);
            }
        }
        __syncthreads();
    }

    // extract w1 (col 100), sum_q (col 101), w2 (row 100), sum_p (row 101)
    if ((lane & 31) == 4 || (lane & 31) == 5) {
        float* dst = ((lane & 31) == 4) ? wrL : sqv;
        #pragma unroll
        for (int reg = 0; reg < 16; ++reg) {
            int row = 32 * wid + (reg & 3) + 8 * (reg >> 2) + 4 * lhi;
            if (row < PP) dst[row] = acc[3][reg];
        }
    }
    if (wid == 3 && lhi == 1) {
        #pragma unroll
        for (int tc = 0; tc < 4; ++tc) {
            int col = 32 * tc + lrow;
            if (col < PP) { wcL[col] = acc[tc][0]; spv[col] = acc[tc][1]; }
        }
    }
    if (tid < 112) vvec[tid] = 1.f;
    __syncthreads();

    // normalize weights; centered norms
    float v1 = 0.f, v2 = 0.f;
    if (tid < PP) {
        v1 = fmaxf(wrL[tid], 0.f) + 0.00101f;
        v2 = fmaxf(wcL[tid], 0.f) + 0.00101f;
    }
    float s1 = v1, s2 = v2;
    #pragma unroll
    for (int off = 32; off; off >>= 1) { s1 += __shfl_down(s1, off); s2 += __shfl_down(s2, off); }
    if ((tid & 63) == 0) { red[tid >> 6] = s1; red[4 + (tid >> 6)] = s2; }
    __syncthreads();
    float t1 = red[0] + red[1], t2 = red[4] + red[5];
    if (tid < PP) {
        wrL[tid] = v1 * (100.f / t1);
        wcL[tid] = v2 * (100.f / t2);
        float sq = sqv[tid], sp = spv[tid];
        qnl[tid] = ws[OFF_QSQ + m * PP + tid] - sq * sq * (1.f / 512.f);
        pnl[tid] = ws[OFF_PSQ + n * PP + tid] - sp * sp * (1.f / 512.f);
    }
    __syncthreads();

    // sqd into acc; block max
    float spc[4], pnc[4];
    #pragma unroll
    for (int tc = 0; tc < 4; ++tc) {
        int col = 32 * tc + lrow;
        bool cv = col < PP;
        spc[tc] = cv ? spv[col] : 0.f;
        pnc[tc] = cv ? pnl[col] : 0.f;
    }
    float mymax = -1e30f;
    #pragma unroll
    for (int reg = 0; reg < 16; ++reg) {
        int row = 32 * wid + (reg & 3) + 8 * (reg >> 2) + 4 * lhi;
        bool rv = row < PP;
        float sqr = rv ? sqv[row] : 0.f;
        float qnr = rv ? qnl[row] : 0.f;
        #pragma unroll
        for (int tc = 0; tc < 4; ++tc) {
            float sqd = qnr + pnc[tc] - 2.f * (acc[tc][reg] - sqr * spc[tc] * (1.f / 512.f));
            acc[tc][reg] = sqd;
            int col = 32 * tc + lrow;
            if (rv && col < PP) mymax = fmaxf(mymax, sqd);
        }
    }
    #pragma unroll
    for (int off = 32; off; off >>= 1) mymax = fmaxf(mymax, __shfl_down(mymax, off));
    __syncthreads();
    if (lane == 0) red[wid] = mymax;
    __syncthreads();
    float scale = fmaxf(fmaxf(red[0], red[1]), fmaxf(red[2], red[3])) + 1e-6f;
    float k2 = (1.f / scale) * (20.f * 1.44269504088896f);

    // Gibbs kernel K = 2^(-sqd*k2), packed bf16 pairs, K rows + KT rows
    #pragma unroll
    for (int tc = 0; tc < 4; ++tc) {
        float kv[16];
        #pragma unroll
        for (int reg = 0; reg < 16; ++reg) kv[reg] = exp2f(-acc[tc][reg] * k2);
        int col = 32 * tc + lrow;
        #pragma unroll
        for (int reg = 0; reg < 16; ++reg) {
            float pv = __shfl_xor(kv[reg], 1);
            int row = 32 * wid + (reg & 3) + 8 * (reg >> 2) + 4 * lhi;
            if (!(lane & 1) && row < PP && col < PP) {
                int j = col >> 1;
                int dw = j + (j >= 25);
                uint pk = (__float_as_uint(kv[reg]) >> 16) | (__float_as_uint(pv) & 0xFFFF0000u);
                *(uint*)&SH[row * 216 + dw * 4] = pk;
            }
        }
        if (col < PP) {
            #pragma unroll
            for (int rp = 0; rp < 8; ++rp) {
                int row0 = 32 * wid + ((2 * rp) & 3) + 8 * (rp >> 1) + 4 * lhi;
                if (row0 < PP) {
                    int jr = row0 >> 1;
                    int dw = jr + (jr >= 25);
                    uint pk = (__float_as_uint(kv[2 * rp]) >> 16) |
                              (__float_as_uint(kv[2 * rp + 1]) & 0xFFFF0000u);
                    *(uint*)&SH[21600 + col * 216 + dw * 4] = pk;
                }
            }
        }
    }
    __syncthreads();

    // linear-domain Sinkhorn: u = wr/(K v), v = wc/(KT u); no transcendentals
    int r_ = tid >> 1, hf = tid & 1;
    bool sact = tid < 200;
    const uint* Kr  = (const uint*)&SH[r_ * 216 + hf * 104];
    const uint* KTr = (const uint*)&SH[21600 + r_ * 216 + hf * 104];
    float wr_own = 0.f, wc_own = 0.f;
    if (sact) { wr_own = wrL[r_]; wc_own = wcL[r_]; }
    int widx = r_ + (r_ >= 50 ? 6 : 0);

    for (int it = 0; it < 50; ++it) {
        if (sact) {
            const float* vp = vvec + hf * 56;
            float sA = 0.f, sB = 0.f;
            #pragma unroll
            for (int q = 0; q < 25; ++q) {
                uint pk = Kr[q];
                sA = fmaf(__uint_as_float(pk << 16), vp[2 * q], sA);
                sB = fmaf(__uint_as_float(pk & 0xFFFF0000u), vp[2 * q + 1], sB);
            }
            float s = sA + sB;
            s += __shfl_xor(s, 1);
            if (!hf) uvec[widx] = wr_own / s;
        }
        __syncthreads();
        if (sact) {
            const float* up = uvec + hf * 56;
            float sA = 0.f, sB = 0.f;
            #pragma unroll
            for (int q = 0; q < 25; ++q) {
                uint pk = KTr[q];
                sA = fmaf(__uint_as_float(pk << 16), up[2 * q], sA);
                sB = fmaf(__uint_as_float(pk & 0xFFFF0000u), up[2 * q + 1], sB);
            }
            float s = sA + sB;
            s += __shfl_xor(s, 1);
            if (!hf) vvec[widx] = wc_own / s;
        }
        __syncthreads();
    }

    // epilogue: logits = 0.125 * sum (1 - sqd) * u_r * 2^(-sqd*k2) * v_c
    float vcl[4];
    #pragma unroll
    for (int tc = 0; tc < 4; ++tc) {
        int col = 32 * tc + lrow;
        vcl[tc] = (col < PP) ? vvec[col + (col >= 50 ? 6 : 0)] : 0.f;
    }
    float lsum = 0.f;
    #pragma unroll
    for (int reg = 0; reg < 16; ++reg) {
        int row = 32 * wid + (reg & 3) + 8 * (reg >> 2) + 4 * lhi;
        float ur = (row < PP) ? uvec[row + (row >= 50 ? 6 : 0)] : 0.f;
        #pragma unroll
        for (int tc = 0; tc < 4; ++tc) {
            float sqd = acc[tc][reg];
            float fl = exp2f(-sqd * k2) * ur * vcl[tc];
            lsum = fmaf(1.f - sqd, fl, lsum);
        }
    }
    #pragma unroll
    for (int off = 32; off; off >>= 1) lsum += __shfl_down(lsum, off);
    __syncthreads();
    if (lane == 0) red[wid] = lsum;
    __syncthreads();
    if (tid == 0)
        ws[OFF_LOGITS + pair] = ((red[0] + red[1]) + (red[2] + red[3])) * 0.125f;
}

// ---------------- K4: log-softmax + loss --------------------------------
__global__ void k_final(const int* __restrict__ label, const float* __restrict__ ws,
                        float* __restrict__ out) {
    int t = threadIdx.x;   // 384 threads
    float contrib = 0.f;
    if (t < NQ) {
        float lg[NW];
        #pragma unroll
        for (int n = 0; n < NW; ++n) lg[n] = ws[OFF_LOGITS + t * NW + n];
        float mx = lg[0];
        #pragma unroll
        for (int n = 1; n < NW; ++n) mx = fmaxf(mx, lg[n]);
        float s = 0.f;
        #pragma unroll
        for (int n = 0; n < NW; ++n) s += expf(lg[n] - mx);
        float lse = mx + logf(s);
        int lab = label[t];
        #pragma unroll
        for (int n = 0; n < NW; ++n) {
            float lp = lg[n] - lse;
            out[t * NW + n] = lp;
            if (n == lab) contrib = -lp;
        }
    }
    #pragma unroll
    for (int off = 32; off; off >>= 1) contrib += __shfl_down(contrib, off);
    __shared__ float red[6];
    if ((t & 63) == 0) red[t >> 6] = contrib;
    __syncthreads();
    if (t == 0) {
        float s = 0.f;
        #pragma unroll
        for (int i = 0; i < 6; ++i) s += red[i];
        out[NQ * NW] = s * (1.f / NQ);
    }
}

extern "C" void kernel_launch(void* const* d_in, const int* in_sizes, int n_in,
                              void* d_out, int out_size, void* d_ws, size_t ws_size,
                              hipStream_t stream) {
    const float* feat  = (const float*)d_in[0];
    const int*   label = (const int*)d_in[1];
    float* out = (float*)d_out;
    float* ws  = (float*)d_ws;
    const float* query = feat + (size_t)NS * CCH * PP;

    k_proto<<<NW * CCH, 128, 0, stream>>>(feat, ws);
    k_qstat<<<NQ, 256, 0, stream>>>(query, ws + OFF_QSQ, ws + OFF_QAVG);
    k_qstat<<<NW, 256, 0, stream>>>(ws + OFF_PROTO, ws + OFF_PSQ, (float*)nullptr);
    k_pair<<<NPAIR, 256, 0, stream>>>(query, ws);
    k_final<<<1, 384, 0, stream>>>(label, ws, out);
}

// Round 5
// 438.396 us; speedup vs baseline: 4.7643x; 1.0677x over previous
//
#include <hip/hip_runtime.h>
#include <math.h>

#define NW   5
#define PRJ  14
#define CCH  512
#define PP   100
#define NQ   375
#define NS   70
#define NPAIR (NQ*NW)

// ws offsets (floats) — total 818,120 floats = 3.27 MB
#define OFF_PROTO   0          // 5*512*100 = 256000
#define OFF_PAVG    256000     // 2560
#define OFF_QAVG    258560     // 192000
#define OFF_QSQ     450560     // 37500
#define OFF_PSQ     488060     // 500
#define OFF_LOGITS  488560     // 1875
#define OFF_PBF16   490440     // 5 protos * 16 kt * 4096 dwords = 327680

typedef short short8 __attribute__((ext_vector_type(8)));
typedef float f32x16 __attribute__((ext_vector_type(16)));
typedef _Float16 f16x2 __attribute__((ext_vector_type(2)));

__device__ __forceinline__ int SWZ(int n) { return n ^ ((n >> 2) & 7); }

// ---------------- K1: proto = mean over shots; proto_avg ----------------
__global__ void k_proto(const float* __restrict__ feat, float* __restrict__ ws) {
    int nc = blockIdx.x;            // n*512 + c
    int n  = nc >> 9;
    int p  = threadIdx.x;
    float s = 0.f;
    if (p < PP) {
        const float* base = feat + (size_t)((n * PRJ) * CCH) * PP + (size_t)(nc & 511) * PP + p;
        #pragma unroll
        for (int k = 0; k < PRJ; ++k) s += base[(size_t)k * CCH * PP];
        s *= (1.f / PRJ);
        ws[OFF_PROTO + nc * PP + p] = s;
    }
    float v = (p < PP) ? s : 0.f;
    #pragma unroll
    for (int off = 32; off; off >>= 1) v += __shfl_down(v, off);
    __shared__ float red[2];
    if ((threadIdx.x & 63) == 0) red[threadIdx.x >> 6] = v;
    __syncthreads();
    if (threadIdx.x == 0) ws[OFF_PAVG + nc] = (red[0] + red[1]) * (1.f / PP);
}

// ------- K2: per-image transpose-stats: sumsq per node (+ optional avg per ch)
__global__ __launch_bounds__(256) void k_qstat(const float* __restrict__ src,
                                               float* __restrict__ dst_sq,
                                               float* __restrict__ dst_avg) {
    __shared__ __align__(16) float t[6400];
    int b = blockIdx.x, tid = threadIdx.x;
    const float* base = src + (size_t)b * CCH * PP;
    float qsq = 0.f;
    for (int c0 = 0; c0 < CCH; c0 += 64) {
        __syncthreads();
        const float4* g = (const float4*)(base + (size_t)c0 * PP);
        for (int i = tid; i < 1600; i += 256) ((float4*)t)[i] = g[i];
        __syncthreads();
        if (tid < PP) {
            #pragma unroll 8
            for (int c = 0; c < 64; ++c) { float x = t[c * PP + tid]; qsq = fmaf(x, x, qsq); }
        } else if (tid >= 128 && tid < 192) {
            int ch = tid - 128;
            const float4* row = (const float4*)(t + ch * PP);
            float s = 0.f;
            #pragma unroll
            for (int i = 0; i < 25; ++i) { float4 v = row[i]; s += (v.x + v.y) + (v.z + v.w); }
            if (dst_avg) dst_avg[(size_t)b * CCH + c0 + ch] = s * (1.f / PP);
        }
    }
    if (tid < PP) dst_sq[b * PP + tid] = qsq;
}

// ------- K2b: pre-convert protos to SWZ'd bf16 hi/lo LDS images ---------
// img[n][kt] = 16KB: [hi plane 8KB][lo plane 8KB]; includes pad cols:
// logical col 100 = pavg (slot 101), col 101 = ones (slot 100), 102.. = 0.
__global__ __launch_bounds__(256) void k_pconv(float* __restrict__ ws) {
    int b = blockIdx.x;          // n*16 + kt
    int n = b >> 4, kt = b & 15;
    int tid = threadIdx.x;
    int c0 = kt * 32;
    uint* img = (uint*)(ws + OFF_PBF16) + (size_t)b * 4096;
    const float* pb = ws + OFF_PROTO + (size_t)n * CCH * PP;
    const float* pavg = ws + OFF_PAVG + n * CCH;
    for (int i = tid; i < 1600; i += 256) {
        int cp = i / 100, col = i - cp * 100;
        float a0 = pb[(size_t)(c0 + 2 * cp) * PP + col];
        float a1 = pb[(size_t)(c0 + 2 * cp + 1) * PP + col];
        uint h0 = __float_as_uint(a0) & 0xFFFF0000u;
        uint h1 = __float_as_uint(a1) & 0xFFFF0000u;
        float r0 = a0 - __uint_as_float(h0);
        float r1 = a1 - __uint_as_float(h1);
        uint hp = (h0 >> 16) | h1;
        uint lp = (__float_as_uint(r0) >> 16) | (__float_as_uint(r1) & 0xFFFF0000u);
        int off = (((cp >> 2) << 7) | SWZ(col)) * 4 + (cp & 3);
        img[off] = hp;
        img[2048 + off] = lp;
    }
    if (tid < 16) {
        int cp = tid;
        float a0 = pavg[c0 + 2 * cp], a1 = pavg[c0 + 2 * cp + 1];
        uint h0 = __float_as_uint(a0) & 0xFFFF0000u;
        uint h1 = __float_as_uint(a1) & 0xFFFF0000u;
        float r0 = a0 - __uint_as_float(h0);
        float r1 = a1 - __uint_as_float(h1);
        uint hp = (h0 >> 16) | h1;
        uint lp = (__float_as_uint(r0) >> 16) | (__float_as_uint(r1) & 0xFFFF0000u);
        int off = (((cp >> 2) << 7) | 101) * 4 + (cp & 3);
        img[off] = hp;
        img[2048 + off] = lp;
    }
    for (int i = tid; i < 896; i += 256) {
        int dw = i & 3; int t2 = i >> 2;
        int s_i = t2 % 28; int u = t2 / 28;     // u 0..7
        int k4 = u & 3, pl = u >> 2;
        int s = 100 + s_i;
        if (s == 101) continue;
        uint val = (s == 100 && pl == 0) ? 0x3F803F80u : 0u;
        img[pl * 2048 + (((k4 << 7) | s) * 4 + dw)] = val;
    }
}

// ------- K3: per-pair: MFMA cost matmul + weights + linear Sinkhorn ------
__global__ __launch_bounds__(256, 3) void k_pair(const float* __restrict__ query,
                                                 float* __restrict__ ws) {
    // SH aliases: tiles during matmul (A_hi 0 / A_lo 8192 / B_hi 16384 / B_lo 24576)
    // then Gibbs K (f16-pair dwords, rows stride 216B) at 0 and KT at 21600
    __shared__ __align__(16) char SH[43200];
    __shared__ __align__(16) float uvec[112], vvec[112];   // halves at [0,50) and [56,106)
    __shared__ float wrL[PP], wcL[PP], qnl[PP], pnl[PP], sqv[PP], spv[PP];
    __shared__ float red[8];

    int pair = blockIdx.x;
    int m = pair / NW;
    int n = pair - m * NW;
    int tid = threadIdx.x;
    int lane = tid & 63, wid = tid >> 6;
    int lrow = lane & 31, lhi = lane >> 5;

    const float* qb = query + (size_t)m * CCH * PP;
    const float* qavg_g = ws + OFF_QAVG + (size_t)m * CCH;
    const uint* pimg = (const uint*)(ws + OFF_PBF16) + (size_t)n * 16 * 4096;

    // init A pad slots once: slot 100 (=SWZ(101)) = ones, slots 102..127 = 0.
    // (slot 101 = SWZ(100) holds qavg, rewritten per k-tile below)
    for (int idx = tid; idx < 224; idx += 256) {
        int s_i = idx % 28; int rest = idx / 28;     // rest 0..7
        int s = 100 + s_i;
        if (s == 101) continue;
        int k4 = rest & 3, pl = rest >> 2;
        uint4 val = (s == 100 && pl == 0)
                  ? make_uint4(0x3F803F80u, 0x3F803F80u, 0x3F803F80u, 0x3F803F80u)
                  : make_uint4(0u, 0u, 0u, 0u);
        *(uint4*)&SH[pl * 8192 + ((k4 << 7) + s) * 16] = val;
    }

    f32x16 acc[4];
    #pragma unroll
    for (int tc = 0; tc < 4; ++tc)
        #pragma unroll
        for (int e = 0; e < 16; ++e) acc[tc][e] = 0.f;

    int arow16 = SWZ(32 * wid + lrow) * 16;
    int bcol16[4];
    #pragma unroll
    for (int tc = 0; tc < 4; ++tc) bcol16[tc] = SWZ(32 * tc + lrow) * 16;

    for (int kt = 0; kt < 16; ++kt) {
        int c0 = kt * 32;
        // A: query f32 -> bf16 hi/lo split, ch-pair packed dwords, SWZ slots
        for (int idx = tid; idx < 400; idx += 256) {
            int cp = idx / 25, n4 = idx - cp * 25;
            const float* src = qb + (size_t)(c0 + 2 * cp) * PP + n4 * 4;
            float4 x0 = *(const float4*)src;
            float4 x1 = *(const float4*)(src + PP);
            const float* p0 = (const float*)&x0;
            const float* p1 = (const float*)&x1;
            int basedw = ((cp >> 2) << 7);
            int dwb = (cp & 3) * 4;
            #pragma unroll
            for (int i4 = 0; i4 < 4; ++i4) {
                int node = n4 * 4 + i4;
                float a0 = p0[i4], a1 = p1[i4];
                uint h0 = __float_as_uint(a0) & 0xFFFF0000u;
                uint h1 = __float_as_uint(a1) & 0xFFFF0000u;
                float r0 = a0 - __uint_as_float(h0);
                float r1 = a1 - __uint_as_float(h1);
                uint hp = (h0 >> 16) | h1;
                uint lp = (__float_as_uint(r0) >> 16) | (__float_as_uint(r1) & 0xFFFF0000u);
                int off = (basedw + SWZ(node)) * 16 + dwb;
                *(uint*)&SH[off] = hp;
                *(uint*)&SH[8192 + off] = lp;
            }
        }
        // A row 100 = qavg (physical slot 101)
        if (tid < 16) {
            int cp = tid;
            float a0 = qavg_g[c0 + 2 * cp], a1 = qavg_g[c0 + 2 * cp + 1];
            uint h0 = __float_as_uint(a0) & 0xFFFF0000u;
            uint h1 = __float_as_uint(a1) & 0xFFFF0000u;
            float r0 = a0 - __uint_as_float(h0);
            float r1 = a1 - __uint_as_float(h1);
            uint hp = (h0 >> 16) | h1;
            uint lp = (__float_as_uint(r0) >> 16) | (__float_as_uint(r1) & 0xFFFF0000u);
            int off = (((cp >> 2) << 7) + 101) * 16 + (cp & 3) * 4;
            *(uint*)&SH[off] = hp;
            *(uint*)&SH[8192 + off] = lp;
        }
        // B: plain copy of pre-converted proto image (16KB)
        {
            const float4* gB = (const float4*)(pimg + (size_t)kt * 4096);
            float4* sB = (float4*)&SH[16384];
            for (int i = tid; i < 1024; i += 256) sB[i] = gB[i];
        }
        __syncthreads();
        #pragma unroll
        for (int s = 0; s < 2; ++s) {
            int kb = (2 * s + lhi) * 2048;
            short8 ah = *(const short8*)&SH[kb + arow16];
            short8 al = *(const short8*)&SH[8192 + kb + arow16];
            #pragma unroll
            for (int tc = 0; tc < 4; ++tc) {
                short8 bh = *(const short8*)&SH[16384 + kb + bcol16[tc]];
                short8 bl = *(const short8*)&SH[24576 + kb + bcol16[tc]];
                acc[tc] = __builtin_amdgcn_mfma_f32_32x32x16_bf16(ah, bh, acc[tc], 0, 0, 0);
                acc[tc] = __builtin_amdgcn_mfma_f32_32x32x16_bf16(ah, bl, acc[tc], 0, 0, 0);
                acc[tc] = __builtin_amdgcn_mfma_f32_32x32x16_bf16(al, bh, acc[tc], 0, 0, 0);
            }
        }
        __syncthreads();
    }

    // extract w1 (col 100), sum_q (col 101), w2 (row 100), sum_p (row 101)
    if ((lane & 31) == 4 || (lane & 31) == 5) {
        float* dst = ((lane & 31) == 4) ? wrL : sqv;
        #pragma unroll
        for (int reg = 0; reg < 16; ++reg) {
            int row = 32 * wid + (reg & 3) + 8 * (reg >> 2) + 4 * lhi;
            if (row < PP) dst[row] = acc[3][reg];
        }
    }
    if (wid == 3 && lhi == 1) {
        #pragma unroll
        for (int tc = 0; tc < 4; ++tc) {
            int col = 32 * tc + lrow;
            if (col < PP) { wcL[col] = acc[tc][0]; spv[col] = acc[tc][1]; }
        }
    }
    if (tid < 112) vvec[tid] = 1.f;
    __syncthreads();

    // normalize weights (prescaled by 2^15 to fold the f16 K scaling)
    float v1 = 0.f, v2 = 0.f;
    if (tid < PP) {
        v1 = fmaxf(wrL[tid], 0.f) + 0.00101f;
        v2 = fmaxf(wcL[tid], 0.f) + 0.00101f;
    }
    float s1 = v1, s2 = v2;
    #pragma unroll
    for (int off = 32; off; off >>= 1) { s1 += __shfl_down(s1, off); s2 += __shfl_down(s2, off); }
    if ((tid & 63) == 0) { red[tid >> 6] = s1; red[4 + (tid >> 6)] = s2; }
    __syncthreads();
    float t1 = red[0] + red[1], t2 = red[4] + red[5];
    if (tid < PP) {
        wrL[tid] = v1 * (100.f / t1) * 32768.f;
        wcL[tid] = v2 * (100.f / t2) * 32768.f;
        float sq = sqv[tid], sp = spv[tid];
        qnl[tid] = ws[OFF_QSQ + m * PP + tid] - sq * sq * (1.f / 512.f);
        pnl[tid] = ws[OFF_PSQ + n * PP + tid] - sp * sp * (1.f / 512.f);
    }
    __syncthreads();

    // sqd into acc; block max
    float spc[4], pnc[4];
    #pragma unroll
    for (int tc = 0; tc < 4; ++tc) {
        int col = 32 * tc + lrow;
        bool cv = col < PP;
        spc[tc] = cv ? spv[col] : 0.f;
        pnc[tc] = cv ? pnl[col] : 0.f;
    }
    float mymax = -1e30f;
    #pragma unroll
    for (int reg = 0; reg < 16; ++reg) {
        int row = 32 * wid + (reg & 3) + 8 * (reg >> 2) + 4 * lhi;
        bool rv = row < PP;
        float sqr = rv ? sqv[row] : 0.f;
        float qnr = rv ? qnl[row] : 0.f;
        #pragma unroll
        for (int tc = 0; tc < 4; ++tc) {
            float sqd = qnr + pnc[tc] - 2.f * (acc[tc][reg] - sqr * spc[tc] * (1.f / 512.f));
            acc[tc][reg] = sqd;
            int col = 32 * tc + lrow;
            if (rv && col < PP) mymax = fmaxf(mymax, sqd);
        }
    }
    #pragma unroll
    for (int off = 32; off; off >>= 1) mymax = fmaxf(mymax, __shfl_down(mymax, off));
    __syncthreads();
    if (lane == 0) red[wid] = mymax;
    __syncthreads();
    float scale = fmaxf(fmaxf(red[0], red[1]), fmaxf(red[2], red[3])) + 1e-6f;
    float k2 = (1.f / scale) * (20.f * 1.44269504088896f);

    // Gibbs kernel K' = 2^(15 - sqd*k2) as f16 pairs (f16 normal range), K rows + KT rows
    #pragma unroll
    for (int tc = 0; tc < 4; ++tc) {
        float kv[16];
        #pragma unroll
        for (int reg = 0; reg < 16; ++reg) kv[reg] = exp2f(fmaf(-acc[tc][reg], k2, 15.f));
        int col = 32 * tc + lrow;
        #pragma unroll
        for (int reg = 0; reg < 16; ++reg) {
            float pv = __shfl_xor(kv[reg], 1);
            int row = 32 * wid + (reg & 3) + 8 * (reg >> 2) + 4 * lhi;
            if (!(lane & 1) && row < PP && col < PP) {
                int j = col >> 1;
                int dw = j + (j >= 25);
                uint pk = __builtin_bit_cast(uint, __builtin_amdgcn_cvt_pkrtz(kv[reg], pv));
                *(uint*)&SH[row * 216 + dw * 4] = pk;
            }
        }
        if (col < PP) {
            #pragma unroll
            for (int rp = 0; rp < 8; ++rp) {
                int row0 = 32 * wid + ((2 * rp) & 3) + 8 * (rp >> 1) + 4 * lhi;
                if (row0 < PP) {
                    int jr = row0 >> 1;
                    int dw = jr + (jr >= 25);
                    uint pk = __builtin_bit_cast(uint,
                        __builtin_amdgcn_cvt_pkrtz(kv[2 * rp], kv[2 * rp + 1]));
                    *(uint*)&SH[21600 + col * 216 + dw * 4] = pk;
                }
            }
        }
    }
    __syncthreads();

    // linear-domain Sinkhorn via v_fma_mix (f16 K operand, f32 accumulate)
    int r_ = tid >> 1, hf = tid & 1;
    bool sact = tid < 200;
    const uint* Kr  = (const uint*)&SH[r_ * 216 + hf * 104];
    const uint* KTr = (const uint*)&SH[21600 + r_ * 216 + hf * 104];
    float wr_own = 0.f, wc_own = 0.f;
    if (sact) { wr_own = wrL[r_]; wc_own = wcL[r_]; }
    int widx = r_ + (r_ >= 50 ? 6 : 0);

    for (int it = 0; it < 50; ++it) {
        if (sact) {
            const float* vp = vvec + hf * 56;
            float sA = 0.f, sB = 0.f;
            #pragma unroll
            for (int q = 0; q < 25; ++q) {
                f16x2 h = __builtin_bit_cast(f16x2, Kr[q]);
                sA = fmaf((float)h[0], vp[2 * q], sA);
                sB = fmaf((float)h[1], vp[2 * q + 1], sB);
            }
            float s = sA + sB;
            s += __shfl_xor(s, 1);
            if (!hf) uvec[widx] = wr_own * __builtin_amdgcn_rcpf(s);
        }
        __syncthreads();
        if (sact) {
            const float* up = uvec + hf * 56;
            float sA = 0.f, sB = 0.f;
            #pragma unroll
            for (int q = 0; q < 25; ++q) {
                f16x2 h = __builtin_bit_cast(f16x2, KTr[q]);
                sA = fmaf((float)h[0], up[2 * q], sA);
                sB = fmaf((float)h[1], up[2 * q + 1], sB);
            }
            float s = sA + sB;
            s += __shfl_xor(s, 1);
            if (!hf) vvec[widx] = wc_own * __builtin_amdgcn_rcpf(s);
        }
        __syncthreads();
    }

    // epilogue: logits = 0.125 * sum (1 - sqd) * u_r * 2^(-sqd*k2) * v_c
    float vcl[4];
    #pragma unroll
    for (int tc = 0; tc < 4; ++tc) {
        int col = 32 * tc + lrow;
        vcl[tc] = (col < PP) ? vvec[col + (col >= 50 ? 6 : 0)] : 0.f;
    }
    float lsum = 0.f;
    #pragma unroll
    for (int reg = 0; reg < 16; ++reg) {
        int row = 32 * wid + (reg & 3) + 8 * (reg >> 2) + 4 * lhi;
        float ur = (row < PP) ? uvec[row + (row >= 50 ? 6 : 0)] : 0.f;
        #pragma unroll
        for (int tc = 0; tc < 4; ++tc) {
            float sqd = acc[tc][reg];
            float fl = exp2f(-sqd * k2) * ur * vcl[tc];
            lsum = fmaf(1.f - sqd, fl, lsum);
        }
    }
    #pragma unroll
    for (int off = 32; off; off >>= 1) lsum += __shfl_down(lsum, off);
    __syncthreads();
    if (lane == 0) red[wid] = lsum;
    __syncthreads();
    if (tid == 0)
        ws[OFF_LOGITS + pair] = ((red[0] + red[1]) + (red[2] + red[3])) * 0.125f;
}

// ---------------- K4: log-softmax + loss --------------------------------
__global__ void k_final(const int* __restrict__ label, const float* __restrict__ ws,
                        float* __restrict__ out) {
    int t = threadIdx.x;   // 384 threads
    float contrib = 0.f;
    if (t < NQ) {
        float lg[NW];
        #pragma unroll
        for (int n = 0; n < NW; ++n) lg[n] = ws[OFF_LOGITS + t * NW + n];
        float mx = lg[0];
        #pragma unroll
        for (int n = 1; n < NW; ++n) mx = fmaxf(mx, lg[n]);
        float s = 0.f;
        #pragma unroll
        for (int n = 0; n < NW; ++n) s += expf(lg[n] - mx);
        float lse = mx + logf(s);
        int lab = label[t];
        #pragma unroll
        for (int n = 0; n < NW; ++n) {
            float lp = lg[n] - lse;
            out[t * NW + n] = lp;
            if (n == lab) contrib = -lp;
        }
    }
    #pragma unroll
    for (int off = 32; off; off >>= 1) contrib += __shfl_down(contrib, off);
    __shared__ float red[6];
    if ((t & 63) == 0) red[t >> 6] = contrib;
    __syncthreads();
    if (t == 0) {
        float s = 0.f;
        #pragma unroll
        for (int i = 0; i < 6; ++i) s += red[i];
        out[NQ * NW] = s * (1.f / NQ);
    }
}

extern "C" void kernel_launch(void* const* d_in, const int* in_sizes, int n_in,
                              void* d_out, int out_size, void* d_ws, size_t ws_size,
                              hipStream_t stream) {
    const float* feat  = (const float*)d_in[0];
    const int*   label = (const int*)d_in[1];
    float* out = (float*)d_out;
    float* ws  = (float*)d_ws;
    const float* query = feat + (size_t)NS * CCH * PP;

    k_proto<<<NW * CCH, 128, 0, stream>>>(feat, ws);
    k_qstat<<<NQ, 256, 0, stream>>>(query, ws + OFF_QSQ, ws + OFF_QAVG);
    k_qstat<<<NW, 256, 0, stream>>>(ws + OFF_PROTO, ws + OFF_PSQ, (float*)nullptr);
    k_pconv<<<NW * 16, 256, 0, stream>>>(ws);
    k_pair<<<NPAIR, 256, 0, stream>>>(query, ws);
    k_final<<<1, 384, 0, stream>>>(label, ws, out);
}

// Round 6
// 293.088 us; speedup vs baseline: 7.1264x; 1.4958x over previous
//
#include <hip/hip_runtime.h>
#include <math.h>

#define NW   5
#define PRJ  14
#define CCH  512
#define PP   100
#define NQ   375
#define NS   70
#define NPAIR (NQ*NW)

// ws offsets (floats) — total 818,120 floats = 3.27 MB
#define OFF_PROTO   0          // 5*512*100 = 256000
#define OFF_PAVG    256000     // 2560
#define OFF_QAVG    258560     // 192000
#define OFF_QSQ     450560     // 37500
#define OFF_PSQ     488060     // 500
#define OFF_LOGITS  488560     // 1875
#define OFF_PBF16   490440     // 5 protos * 16 kt * 4096 dwords = 327680

typedef short short8 __attribute__((ext_vector_type(8)));
typedef float f32x16 __attribute__((ext_vector_type(16)));
typedef _Float16 f16x2 __attribute__((ext_vector_type(2)));

__device__ __forceinline__ int SWZ(int n) { return n ^ ((n >> 2) & 7); }

// ---------------- K1: proto = mean over shots; proto_avg ----------------
__global__ void k_proto(const float* __restrict__ feat, float* __restrict__ ws) {
    int nc = blockIdx.x;            // n*512 + c
    int n  = nc >> 9;
    int p  = threadIdx.x;
    float s = 0.f;
    if (p < PP) {
        const float* base = feat + (size_t)((n * PRJ) * CCH) * PP + (size_t)(nc & 511) * PP + p;
        #pragma unroll
        for (int k = 0; k < PRJ; ++k) s += base[(size_t)k * CCH * PP];
        s *= (1.f / PRJ);
        ws[OFF_PROTO + nc * PP + p] = s;
    }
    float v = (p < PP) ? s : 0.f;
    #pragma unroll
    for (int off = 32; off; off >>= 1) v += __shfl_down(v, off);
    __shared__ float red[2];
    if ((threadIdx.x & 63) == 0) red[threadIdx.x >> 6] = v;
    __syncthreads();
    if (threadIdx.x == 0) ws[OFF_PAVG + nc] = (red[0] + red[1]) * (1.f / PP);
}

// ------- K2: per-image transpose-stats: sumsq per node (+ optional avg per ch)
__global__ __launch_bounds__(256) void k_qstat(const float* __restrict__ src,
                                               float* __restrict__ dst_sq,
                                               float* __restrict__ dst_avg) {
    __shared__ __align__(16) float t[6400];
    int b = blockIdx.x, tid = threadIdx.x;
    const float* base = src + (size_t)b * CCH * PP;
    float qsq = 0.f;
    for (int c0 = 0; c0 < CCH; c0 += 64) {
        __syncthreads();
        const float4* g = (const float4*)(base + (size_t)c0 * PP);
        for (int i = tid; i < 1600; i += 256) ((float4*)t)[i] = g[i];
        __syncthreads();
        if (tid < PP) {
            #pragma unroll 8
            for (int c = 0; c < 64; ++c) { float x = t[c * PP + tid]; qsq = fmaf(x, x, qsq); }
        } else if (tid >= 128 && tid < 192) {
            int ch = tid - 128;
            const float4* row = (const float4*)(t + ch * PP);
            float s = 0.f;
            #pragma unroll
            for (int i = 0; i < 25; ++i) { float4 v = row[i]; s += (v.x + v.y) + (v.z + v.w); }
            if (dst_avg) dst_avg[(size_t)b * CCH + c0 + ch] = s * (1.f / PP);
        }
    }
    if (tid < PP) dst_sq[b * PP + tid] = qsq;
}

// ------- K2b: pre-convert protos to SWZ'd bf16 hi/lo LDS images ---------
__global__ __launch_bounds__(256) void k_pconv(float* __restrict__ ws) {
    int b = blockIdx.x;          // n*16 + kt
    int n = b >> 4, kt = b & 15;
    int tid = threadIdx.x;
    int c0 = kt * 32;
    uint* img = (uint*)(ws + OFF_PBF16) + (size_t)b * 4096;
    const float* pb = ws + OFF_PROTO + (size_t)n * CCH * PP;
    const float* pavg = ws + OFF_PAVG + n * CCH;
    for (int i = tid; i < 1600; i += 256) {
        int cp = i / 100, col = i - cp * 100;
        float a0 = pb[(size_t)(c0 + 2 * cp) * PP + col];
        float a1 = pb[(size_t)(c0 + 2 * cp + 1) * PP + col];
        uint h0 = __float_as_uint(a0) & 0xFFFF0000u;
        uint h1 = __float_as_uint(a1) & 0xFFFF0000u;
        float r0 = a0 - __uint_as_float(h0);
        float r1 = a1 - __uint_as_float(h1);
        uint hp = (h0 >> 16) | h1;
        uint lp = (__float_as_uint(r0) >> 16) | (__float_as_uint(r1) & 0xFFFF0000u);
        int off = (((cp >> 2) << 7) | SWZ(col)) * 4 + (cp & 3);
        img[off] = hp;
        img[2048 + off] = lp;
    }
    if (tid < 16) {
        int cp = tid;
        float a0 = pavg[c0 + 2 * cp], a1 = pavg[c0 + 2 * cp + 1];
        uint h0 = __float_as_uint(a0) & 0xFFFF0000u;
        uint h1 = __float_as_uint(a1) & 0xFFFF0000u;
        float r0 = a0 - __uint_as_float(h0);
        float r1 = a1 - __uint_as_float(h1);
        uint hp = (h0 >> 16) | h1;
        uint lp = (__float_as_uint(r0) >> 16) | (__float_as_uint(r1) & 0xFFFF0000u);
        int off = (((cp >> 2) << 7) | 101) * 4 + (cp & 3);
        img[off] = hp;
        img[2048 + off] = lp;
    }
    for (int i = tid; i < 896; i += 256) {
        int dw = i & 3; int t2 = i >> 2;
        int s_i = t2 % 28; int u = t2 / 28;     // u 0..7
        int k4 = u & 3, pl = u >> 2;
        int s = 100 + s_i;
        if (s == 101) continue;
        uint val = (s == 100 && pl == 0) ? 0x3F803F80u : 0u;
        img[pl * 2048 + (((k4 << 7) | s) * 4 + dw)] = val;
    }
}

// ------- K3: per-pair: MFMA cost matmul + weights + reg-resident Sinkhorn
__global__ __launch_bounds__(256, 4) void k_pair(const float* __restrict__ query,
                                                 float* __restrict__ ws) {
    // SH union: matmul tiles (A_hi 0 / A_lo 8192 / B_hi 16384 / B_lo 24576, 32KB)
    // then Gibbs K f16-pair rows: stride 56 dw, col-halves at +0 and +28 (22.4KB)
    __shared__ __align__(16) char SH[32768];
    __shared__ __align__(16) float uvec[112], vvec[112];   // halves at [0,50) and [56,106)
    __shared__ float wrL[PP], wcL[PP], qnl[PP], pnl[PP], sqv[PP], spv[PP];
    __shared__ float red[8];

    uint* Kst = (uint*)SH;

    int pair = blockIdx.x;
    int m = pair / NW;
    int n = pair - m * NW;
    int tid = threadIdx.x;
    int lane = tid & 63, wid = tid >> 6;
    int lrow = lane & 31, lhi = lane >> 5;

    const float* qb = query + (size_t)m * CCH * PP;
    const float* qavg_g = ws + OFF_QAVG + (size_t)m * CCH;
    const uint* pimg = (const uint*)(ws + OFF_PBF16) + (size_t)n * 16 * 4096;

    // init A pad slots once: slot 100 (=SWZ(101)) = ones, slots 102..127 = 0.
    // (slot 101 = SWZ(100) holds qavg, rewritten per k-tile below)
    for (int idx = tid; idx < 224; idx += 256) {
        int s_i = idx % 28; int rest = idx / 28;     // rest 0..7
        int s = 100 + s_i;
        if (s == 101) continue;
        int k4 = rest & 3, pl = rest >> 2;
        uint4 val = (s == 100 && pl == 0)
                  ? make_uint4(0x3F803F80u, 0x3F803F80u, 0x3F803F80u, 0x3F803F80u)
                  : make_uint4(0u, 0u, 0u, 0u);
        *(uint4*)&SH[pl * 8192 + ((k4 << 7) + s) * 16] = val;
    }

    f32x16 acc[4];
    #pragma unroll
    for (int tc = 0; tc < 4; ++tc)
        #pragma unroll
        for (int e = 0; e < 16; ++e) acc[tc][e] = 0.f;

    int arow16 = SWZ(32 * wid + lrow) * 16;
    int bcol16[4];
    #pragma unroll
    for (int tc = 0; tc < 4; ++tc) bcol16[tc] = SWZ(32 * tc + lrow) * 16;

    for (int kt = 0; kt < 16; ++kt) {
        int c0 = kt * 32;
        // A: query f32 -> bf16 hi/lo split, ch-pair packed dwords, SWZ slots
        for (int idx = tid; idx < 400; idx += 256) {
            int cp = idx / 25, n4 = idx - cp * 25;
            const float* src = qb + (size_t)(c0 + 2 * cp) * PP + n4 * 4;
            float4 x0 = *(const float4*)src;
            float4 x1 = *(const float4*)(src + PP);
            const float* p0 = (const float*)&x0;
            const float* p1 = (const float*)&x1;
            int basedw = ((cp >> 2) << 7);
            int dwb = (cp & 3) * 4;
            #pragma unroll
            for (int i4 = 0; i4 < 4; ++i4) {
                int node = n4 * 4 + i4;
                float a0 = p0[i4], a1 = p1[i4];
                uint h0 = __float_as_uint(a0) & 0xFFFF0000u;
                uint h1 = __float_as_uint(a1) & 0xFFFF0000u;
                float r0 = a0 - __uint_as_float(h0);
                float r1 = a1 - __uint_as_float(h1);
                uint hp = (h0 >> 16) | h1;
                uint lp = (__float_as_uint(r0) >> 16) | (__float_as_uint(r1) & 0xFFFF0000u);
                int off = (basedw + SWZ(node)) * 16 + dwb;
                *(uint*)&SH[off] = hp;
                *(uint*)&SH[8192 + off] = lp;
            }
        }
        // A row 100 = qavg (physical slot 101)
        if (tid < 16) {
            int cp = tid;
            float a0 = qavg_g[c0 + 2 * cp], a1 = qavg_g[c0 + 2 * cp + 1];
            uint h0 = __float_as_uint(a0) & 0xFFFF0000u;
            uint h1 = __float_as_uint(a1) & 0xFFFF0000u;
            float r0 = a0 - __uint_as_float(h0);
            float r1 = a1 - __uint_as_float(h1);
            uint hp = (h0 >> 16) | h1;
            uint lp = (__float_as_uint(r0) >> 16) | (__float_as_uint(r1) & 0xFFFF0000u);
            int off = (((cp >> 2) << 7) + 101) * 16 + (cp & 3) * 4;
            *(uint*)&SH[off] = hp;
            *(uint*)&SH[8192 + off] = lp;
        }
        // B: plain copy of pre-converted proto image (16KB)
        {
            const float4* gB = (const float4*)(pimg + (size_t)kt * 4096);
            float4* sB = (float4*)&SH[16384];
            for (int i = tid; i < 1024; i += 256) sB[i] = gB[i];
        }
        __syncthreads();
        #pragma unroll
        for (int s = 0; s < 2; ++s) {
            int kb = (2 * s + lhi) * 2048;
            short8 ah = *(const short8*)&SH[kb + arow16];
            short8 al = *(const short8*)&SH[8192 + kb + arow16];
            #pragma unroll
            for (int tc = 0; tc < 4; ++tc) {
                short8 bh = *(const short8*)&SH[16384 + kb + bcol16[tc]];
                short8 bl = *(const short8*)&SH[24576 + kb + bcol16[tc]];
                acc[tc] = __builtin_amdgcn_mfma_f32_32x32x16_bf16(ah, bh, acc[tc], 0, 0, 0);
                acc[tc] = __builtin_amdgcn_mfma_f32_32x32x16_bf16(ah, bl, acc[tc], 0, 0, 0);
                acc[tc] = __builtin_amdgcn_mfma_f32_32x32x16_bf16(al, bh, acc[tc], 0, 0, 0);
            }
        }
        __syncthreads();
    }

    // extract w1 (col 100), sum_q (col 101), w2 (row 100), sum_p (row 101)
    if ((lane & 31) == 4 || (lane & 31) == 5) {
        float* dst = ((lane & 31) == 4) ? wrL : sqv;
        #pragma unroll
        for (int reg = 0; reg < 16; ++reg) {
            int row = 32 * wid + (reg & 3) + 8 * (reg >> 2) + 4 * lhi;
            if (row < PP) dst[row] = acc[3][reg];
        }
    }
    if (wid == 3 && lhi == 1) {
        #pragma unroll
        for (int tc = 0; tc < 4; ++tc) {
            int col = 32 * tc + lrow;
            if (col < PP) { wcL[col] = acc[tc][0]; spv[col] = acc[tc][1]; }
        }
    }
    if (tid < 112) vvec[tid] = 1.f;
    __syncthreads();

    // normalize weights (prescaled by 2^15 to fold the f16 K scaling)
    float v1 = 0.f, v2 = 0.f;
    if (tid < PP) {
        v1 = fmaxf(wrL[tid], 0.f) + 0.00101f;
        v2 = fmaxf(wcL[tid], 0.f) + 0.00101f;
    }
    float s1 = v1, s2 = v2;
    #pragma unroll
    for (int off = 32; off; off >>= 1) { s1 += __shfl_down(s1, off); s2 += __shfl_down(s2, off); }
    if ((tid & 63) == 0) { red[tid >> 6] = s1; red[4 + (tid >> 6)] = s2; }
    __syncthreads();
    float t1 = red[0] + red[1], t2 = red[4] + red[5];
    if (tid < PP) {
        wrL[tid] = v1 * (100.f / t1) * 32768.f;
        wcL[tid] = v2 * (100.f / t2) * 32768.f;
        float sq = sqv[tid], sp = spv[tid];
        qnl[tid] = ws[OFF_QSQ + m * PP + tid] - sq * sq * (1.f / 512.f);
        pnl[tid] = ws[OFF_PSQ + n * PP + tid] - sp * sp * (1.f / 512.f);
    }
    __syncthreads();

    // sqd into acc; block max
    float spc[4], pnc[4];
    #pragma unroll
    for (int tc = 0; tc < 4; ++tc) {
        int col = 32 * tc + lrow;
        bool cv = col < PP;
        spc[tc] = cv ? spv[col] : 0.f;
        pnc[tc] = cv ? pnl[col] : 0.f;
    }
    float mymax = -1e30f;
    #pragma unroll
    for (int reg = 0; reg < 16; ++reg) {
        int row = 32 * wid + (reg & 3) + 8 * (reg >> 2) + 4 * lhi;
        bool rv = row < PP;
        float sqr = rv ? sqv[row] : 0.f;
        float qnr = rv ? qnl[row] : 0.f;
        #pragma unroll
        for (int tc = 0; tc < 4; ++tc) {
            float sqd = qnr + pnc[tc] - 2.f * (acc[tc][reg] - sqr * spc[tc] * (1.f / 512.f));
            acc[tc][reg] = sqd;
            int col = 32 * tc + lrow;
            if (rv && col < PP) mymax = fmaxf(mymax, sqd);
        }
    }
    #pragma unroll
    for (int off = 32; off; off >>= 1) mymax = fmaxf(mymax, __shfl_down(mymax, off));
    __syncthreads();
    if (lane == 0) red[wid] = mymax;
    __syncthreads();
    float scale = fmaxf(fmaxf(red[0], red[1]), fmaxf(red[2], red[3])) + 1e-6f;
    float k2 = (1.f / scale) * (20.f * 1.44269504088896f);

    // Gibbs K' = 2^(15 - sqd*k2) f16-pair rows -> Kst (tiles are dead)
    #pragma unroll
    for (int tc = 0; tc < 4; ++tc) {
        float kv[16];
        #pragma unroll
        for (int reg = 0; reg < 16; ++reg) kv[reg] = exp2f(fmaf(-acc[tc][reg], k2, 15.f));
        int col = 32 * tc + lrow;
        #pragma unroll
        for (int reg = 0; reg < 16; ++reg) {
            float pv = __shfl_xor(kv[reg], 1);
            int row = 32 * wid + (reg & 3) + 8 * (reg >> 2) + 4 * lhi;
            if (!(lane & 1) && row < PP && col < PP) {
                int j = col >> 1;
                int dw = (j < 25) ? j : (j + 3);     // halves at +0 / +28
                uint pk = __builtin_bit_cast(uint, __builtin_amdgcn_cvt_pkrtz(kv[reg], pv));
                Kst[row * 56 + dw] = pk;
            }
        }
    }
    __syncthreads();

    // load K row-half and gathered col-half into registers
    int r_ = tid >> 1, hf = tid & 1;
    bool sact = tid < 200;
    int widx = r_ + (r_ >= 50 ? 6 : 0);
    uint Kr[25], KTr[25];
    float wr_own = 0.f, wc_own = 0.f;
    if (sact) {
        const uint* rp = Kst + r_ * 56 + 28 * hf;
        #pragma unroll
        for (int q = 0; q < 25; ++q) Kr[q] = rp[q];
        int j = r_ >> 1;
        int dwc = (j < 25) ? j : (j + 3);
        int sh = (r_ & 1) * 16;
        const uint* cp0 = Kst + (50 * hf) * 56 + dwc;
        #pragma unroll
        for (int q = 0; q < 25; ++q) {
            uint d0 = cp0[(2 * q) * 56];
            uint d1 = cp0[(2 * q + 1) * 56];
            KTr[q] = ((d0 >> sh) & 0xFFFFu) | (((d1 >> sh) & 0xFFFFu) << 16);
        }
        wr_own = wrL[r_];
        wc_own = wcL[r_];
    }
    __syncthreads();

    // linear Sinkhorn, K in registers; only u/v broadcasts touch LDS
    for (int it = 0; it < 50; ++it) {
        if (sact) {
            const float* vp = vvec + hf * 56;
            float sA = 0.f, sB = 0.f;
            #pragma unroll
            for (int q = 0; q < 25; ++q) {
                f16x2 h = __builtin_bit_cast(f16x2, Kr[q]);
                sA = fmaf((float)h[0], vp[2 * q], sA);
                sB = fmaf((float)h[1], vp[2 * q + 1], sB);
            }
            float s = sA + sB;
            s += __shfl_xor(s, 1);
            if (!hf) uvec[widx] = wr_own * __builtin_amdgcn_rcpf(s);
        }
        __syncthreads();
        if (sact) {
            const float* up = uvec + hf * 56;
            float sA = 0.f, sB = 0.f;
            #pragma unroll
            for (int q = 0; q < 25; ++q) {
                f16x2 h = __builtin_bit_cast(f16x2, KTr[q]);
                sA = fmaf((float)h[0], up[2 * q], sA);
                sB = fmaf((float)h[1], up[2 * q + 1], sB);
            }
            float s = sA + sB;
            s += __shfl_xor(s, 1);
            if (!hf) vvec[widx] = wc_own * __builtin_amdgcn_rcpf(s);
        }
        __syncthreads();
    }

    // epilogue in Sinkhorn layout: sqd recovered from stored K'
    // sqd = (15 - log2(K'))/k2 ; contribution (1-sqd)*K'*u*v*2^-15
    float lsum = 0.f;
    if (sact) {
        float ur = uvec[widx];
        const float* vp = vvec + hf * 56;
        float rk2 = scale * (1.f / (20.f * 1.44269504088896f));
        #pragma unroll
        for (int q = 0; q < 25; ++q) {
            f16x2 h = __builtin_bit_cast(f16x2, Kr[q]);
            float k0 = (float)h[0], k1 = (float)h[1];
            float sq0 = (15.f - __log2f(k0)) * rk2;
            float sq1 = (15.f - __log2f(k1)) * rk2;
            lsum = fmaf((1.f - sq0) * k0, vp[2 * q], lsum);
            lsum = fmaf((1.f - sq1) * k1, vp[2 * q + 1], lsum);
        }
        lsum *= ur;
    }
    #pragma unroll
    for (int off = 32; off; off >>= 1) lsum += __shfl_down(lsum, off);
    if (lane == 0) red[wid] = lsum;
    __syncthreads();
    if (tid == 0)
        ws[OFF_LOGITS + pair] = ((red[0] + red[1]) + (red[2] + red[3])) * (0.125f / 32768.f);
}

// ---------------- K4: log-softmax + loss --------------------------------
__global__ void k_final(const int* __restrict__ label, const float* __restrict__ ws,
                        float* __restrict__ out) {
    int t = threadIdx.x;   // 384 threads
    float contrib = 0.f;
    if (t < NQ) {
        float lg[NW];
        #pragma unroll
        for (int n = 0; n < NW; ++n) lg[n] = ws[OFF_LOGITS + t * NW + n];
        float mx = lg[0];
        #pragma unroll
        for (int n = 1; n < NW; ++n) mx = fmaxf(mx, lg[n]);
        float s = 0.f;
        #pragma unroll
        for (int n = 0; n < NW; ++n) s += expf(lg[n] - mx);
        float lse = mx + logf(s);
        int lab = label[t];
        #pragma unroll
        for (int n = 0; n < NW; ++n) {
            float lp = lg[n] - lse;
            out[t * NW + n] = lp;
            if (n == lab) contrib = -lp;
        }
    }
    #pragma unroll
    for (int off = 32; off; off >>= 1) contrib += __shfl_down(contrib, off);
    __shared__ float red[6];
    if ((t & 63) == 0) red[t >> 6] = contrib;
    __syncthreads();
    if (t == 0) {
        float s = 0.f;
        #pragma unroll
        for (int i = 0; i < 6; ++i) s += red[i];
        out[NQ * NW] = s * (1.f / NQ);
    }
}

extern "C" void kernel_launch(void* const* d_in, const int* in_sizes, int n_in,
                              void* d_out, int out_size, void* d_ws, size_t ws_size,
                              hipStream_t stream) {
    const float* feat  = (const float*)d_in[0];
    const int*   label = (const int*)d_in[1];
    float* out = (float*)d_out;
    float* ws  = (float*)d_ws;
    const float* query = feat + (size_t)NS * CCH * PP;

    k_proto<<<NW * CCH, 128, 0, stream>>>(feat, ws);
    k_qstat<<<NQ, 256, 0, stream>>>(query, ws + OFF_QSQ, ws + OFF_QAVG);
    k_qstat<<<NW, 256, 0, stream>>>(ws + OFF_PROTO, ws + OFF_PSQ, (float*)nullptr);
    k_pconv<<<NW * 16, 256, 0, stream>>>(ws);
    k_pair<<<NPAIR, 256, 0, stream>>>(query, ws);
    k_final<<<1, 384, 0, stream>>>(label, ws, out);
}